// Round 17
// baseline (309.915 us; speedup 1.0000x reference)
//
#include <hip/hip_runtime.h>
#include <hip/hip_bf16.h>
#include <math.h>

constexpr int BB = 8, CCH = 192, IH = 128, IW = 128;
constexpr int WSZ = 8;
constexpr int NWIN = 256;
constexpr int NH = 6, HDIM = 32;
constexpr int NPIX = IH * IW;
constexpr int TOPK = 13107;

typedef __attribute__((ext_vector_type(8))) short bf16x8;
typedef __attribute__((ext_vector_type(4))) float f32x4;
typedef __attribute__((ext_vector_type(4))) unsigned short u16x4;
typedef __attribute__((ext_vector_type(8))) unsigned short u16x8;

__device__ __forceinline__ unsigned short f2bf(float f) {
    __hip_bfloat16 h = __float2bfloat16(f);
    return __builtin_bit_cast(unsigned short, h);
}
__device__ __forceinline__ float bf2f(unsigned short u) {
    return __uint_as_float((unsigned)u << 16);
}
__device__ __forceinline__ unsigned monot(float f) {
    unsigned u = __float_as_uint(f);
    return (u & 0x80000000u) ? ~u : (u | 0x80000000u);
}

// ---------------------------------------------------------------------------
// MEGA1: role-fused launch: {kw weight bf16 convert} + {k1 top-k pool rows}
//        || {k0x transpose tiles}. Block = 512 threads.
//   k1 new structure: sweep1 = hist(var) + pool x at weight 1.0;
//                     sweep2 = var-only (L2-hot), subtract 0.4x for out-set.
// ---------------------------------------------------------------------------
struct K1Smem {
    unsigned histP[2][2048];
    unsigned hist256[256];
    unsigned wtot[8];
    unsigned s_prefix, s_rem, s_cnt, s_thr, s_need;
    unsigned candKey[320], candIdx[320];
    unsigned cand_cnt, eq_cnt;
    unsigned eq_idx[64];
    float pooled_s[256];
};
struct K0Smem {
    unsigned short T[64][200];
};
constexpr size_t MEGA1_SMEM = sizeof(K0Smem) > sizeof(K1Smem) ? sizeof(K0Smem) : sizeof(K1Smem);

__global__ __launch_bounds__(512) void mega1(const float* __restrict__ x,
                                             const float* __restrict__ var,
                                             float* __restrict__ pooled,
                                             unsigned short* __restrict__ xt,
                                             const float* __restrict__ qkv_w,
                                             const float* __restrict__ proj_w,
                                             unsigned short* __restrict__ wbf,
                                             int fast) {
    __shared__ __align__(16) char smem[MEGA1_SMEM];
    int id = blockIdx.x;
    int tid = threadIdx.x;
    int wv = tid >> 6, lane = tid & 63;

    if (id < 72) {
        int i4 = id * 512 + tid;
        float4 v = (i4 < 27648) ? ((const float4*)qkv_w)[i4]
                                : ((const float4*)proj_w)[i4 - 27648];
        u16x4 pk = { f2bf(v.x), f2bf(v.y), f2bf(v.z), f2bf(v.w) };
        ((u16x4*)wbf)[i4] = pk;
        return;
    }
    id -= 72;

    int role, sub;
    if (fast) {
        int g = id / 7, r = id % 7;
        if (r < 3) { role = 0; sub = 3 * g + r; }
        else       { role = 1; sub = 4 * g + (r - 3); }
    } else {
        role = 0; sub = id;
    }

    if (role == 1) {
        K0Smem& S0 = *(K0Smem*)smem;
        int b = sub >> 8, px0 = (sub & 255) * 64;
        int px = tid & 63, cg = tid >> 6;
#pragma unroll
        for (int j8 = 0; j8 < 3; ++j8) {
            u16x8 pk;
#pragma unroll
            for (int j = 0; j < 8; ++j)
                pk[j] = f2bf(x[(size_t)(b * CCH + cg * 24 + j8 * 8 + j) * NPIX + px0 + px]);
            *(u16x8*)&S0.T[px][cg * 24 + j8 * 8] = pk;
        }
        __syncthreads();
#pragma unroll
        for (int i = 0; i < 3; ++i) {
            int u = tid + 512 * i;
            int p2 = u / 24, cb = u % 24;
            *(u16x8*)&xt[((size_t)(b * NPIX) + px0 + p2) * CCH + cb * 8] = *(const u16x8*)&S0.T[p2][cb * 8];
        }
        return;
    }

    // ---- k1: exact top-k threshold + masked pool ----
    K1Smem& S = *(K1Smem*)smem;
    int row = sub;
    const float4* vrow4 = (const float4*)(var + (size_t)row * NPIX);
    const float4* xrow4 = (const float4*)(x + (size_t)row * NPIX);
    const float* xrow = x + (size_t)row * NPIX;
    constexpr int CAP = 320;

    for (int i = tid; i < 2 * 2048; i += 512) ((unsigned*)S.histP)[i] = 0;
    if (tid < 256) S.pooled_s[tid] = 0.f;
    if (tid == 0) { S.cand_cnt = 0; S.eq_cnt = 0; }
    __syncthreads();

    // sweep 1: 12-bit histogram of var + pool x at weight 1.0 (mask-free)
    int hc = lane & 1;
#pragma unroll
    for (int j = 0; j < 8; ++j) {
        float4 v4 = vrow4[tid + 512 * j];
        float4 x4 = xrow4[tid + 512 * j];
        float vv[4] = {v4.x, v4.y, v4.z, v4.w};
#pragma unroll
        for (int c = 0; c < 4; ++c) {
            unsigned bk = monot(vv[c]) >> 20;
            atomicAdd(&S.histP[hc][bk >> 1], 1u << ((bk & 1) << 4));
        }
        float part = x4.x + x4.y + x4.z + x4.w;
        part += __shfl_xor(part, 1);
        part += __shfl_xor(part, 32);
        if ((lane & 1) == 0 && lane < 32)
            atomicAdd(&S.pooled_s[(2 * j + (tid >> 8)) * 16 + ((tid >> 1) & 15)], part);
    }
    __syncthreads();

    // scan 4096 buckets: thread owns [8*tid, 8*tid+7]
    {
        unsigned h8[8]; unsigned tsum = 0;
#pragma unroll
        for (int w = 0; w < 4; ++w) {
            unsigned w0 = S.histP[0][tid * 4 + w];
            unsigned w1 = S.histP[1][tid * 4 + w];
            h8[2 * w]     = (w0 & 0xFFFFu) + (w1 & 0xFFFFu);
            h8[2 * w + 1] = (w0 >> 16) + (w1 >> 16);
            tsum += h8[2 * w] + h8[2 * w + 1];
        }
        unsigned s = tsum;
#pragma unroll
        for (int off = 1; off < 64; off <<= 1) {
            unsigned t = __shfl(s, lane + off);
            if (lane + off < 64) s += t;
        }
        if (lane == 0) S.wtot[wv] = s;
        __syncthreads();
        unsigned crossTot = 0;
        for (int w = wv + 1; w < 8; ++w) crossTot += S.wtot[w];
        unsigned above = crossTot + (s - tsum);
        if (above < TOPK && above + tsum >= TOPK) {
            unsigned cum = above;
            for (int i = 7; i >= 0; --i) {
                if (cum < TOPK && cum + h8[i] >= TOPK) {
                    S.s_prefix = (unsigned)(tid * 8 + i);
                    S.s_rem = TOPK - cum;
                    S.s_cnt = h8[i];
                }
                cum += h8[i];
            }
        }
    }
    __syncthreads();

    unsigned prefix = S.s_prefix, rem2 = S.s_rem, cnt = S.s_cnt;
    int prefbits = 12;

    // fallback refinement (normally 0 iterations)
    while (cnt > CAP && prefbits < 32) {
        int nb = (32 - prefbits >= 8) ? 8 : (32 - prefbits);
        int nbuck = 1 << nb;
        __syncthreads();
        for (int i = tid; i < nbuck; i += 512) S.hist256[i] = 0;
        __syncthreads();
        int shift = 32 - prefbits - nb;
#pragma unroll
        for (int j = 0; j < 8; ++j) {
            float4 v4 = vrow4[tid + 512 * j];
            float vv[4] = {v4.x, v4.y, v4.z, v4.w};
#pragma unroll
            for (int c = 0; c < 4; ++c) {
                unsigned mm = monot(vv[c]);
                if ((mm >> (nb + shift)) == prefix)
                    atomicAdd(&S.hist256[(mm >> shift) & (nbuck - 1)], 1u);
            }
        }
        __syncthreads();
        if (wv == 0) {
            int bpl = nbuck > 64 ? nbuck / 64 : 1;
            int nlanes = nbuck / bpl;
            unsigned hh[4] = {0, 0, 0, 0};
            unsigned lsum = 0;
#pragma unroll
            for (int i = 0; i < 4; ++i) {
                if (i < bpl && lane < nlanes) hh[i] = S.hist256[lane * bpl + i];
                lsum += hh[i];
            }
            unsigned s = lsum;
#pragma unroll
            for (int off = 1; off < 64; off <<= 1) {
                unsigned t = __shfl(s, lane + off);
                if (lane + off < 64) s += t;
            }
            unsigned above = s - lsum;
            if (lane < nlanes && above < rem2 && above + lsum >= rem2) {
                unsigned cum = above;
                for (int i = bpl - 1; i >= 0; --i) {
                    if (cum < rem2 && cum + hh[i] >= rem2) {
                        S.s_prefix = (prefix << nb) | (unsigned)(lane * bpl + i);
                        S.s_rem = rem2 - cum;
                        S.s_cnt = hh[i];
                    }
                    cum += hh[i];
                }
            }
        }
        __syncthreads();
        prefix = S.s_prefix; rem2 = S.s_rem; cnt = S.s_cnt;
        prefbits += nb;
    }

    int pshift = 32 - prefbits;

    // sweep 2 (var-only, L2-hot): subtract 0.4x for strictly-below pixels;
    // collect crossing-bucket candidates.
#pragma unroll
    for (int j = 0; j < 8; ++j) {
        float4 v4 = vrow4[tid + 512 * j];
        float vv[4] = {v4.x, v4.y, v4.z, v4.w};
#pragma unroll
        for (int c = 0; c < 4; ++c) {
            unsigned mm = monot(vv[c]);
            unsigned g = (pshift == 0) ? mm : (mm >> pshift);
            if (g < prefix) {
                unsigned idx = (unsigned)(4 * tid + 2048 * j + c);
                int y = (int)(idx >> 7), xx = (int)(idx & 127);
                atomicAdd(&S.pooled_s[(y >> 3) * 16 + (xx >> 3)], -0.4f * xrow[idx]);
            } else if (g == prefix) {
                unsigned pos = atomicAdd(&S.cand_cnt, 1u);
                if (pos < CAP) {
                    S.candKey[pos] = mm;
                    S.candIdx[pos] = (unsigned)(4 * tid + 2048 * j + c);
                }
            }
        }
    }
    __syncthreads();

    // exact threshold among candidates (rank via LDS broadcast)
    int cc = (int)min(S.cand_cnt, (unsigned)CAP);
    for (int ci = tid; ci < cc; ci += 512) {
        unsigned my = S.candKey[ci];
        unsigned kgt = 0, keq = 0;
        for (int e = 0; e < cc; ++e) {
            unsigned o = S.candKey[e];
            kgt += (o > my);
            keq += (o == my);
        }
        if (kgt < rem2 && kgt + keq >= rem2) {
            S.s_thr = my;
            S.s_need = rem2 - kgt;
        }
    }
    __syncthreads();
    unsigned thr = S.s_thr, need_eq = S.s_need;
    for (int ci = tid; ci < cc; ci += 512)
        if (S.candKey[ci] == thr) {
            unsigned pos = atomicAdd(&S.eq_cnt, 1u);
            if (pos < 64) S.eq_idx[pos] = S.candIdx[ci];
        }
    __syncthreads();
    int ecnt = (int)min(S.eq_cnt, 64u);
    if (tid == 0) {
        for (int a = 1; a < ecnt; ++a) {
            unsigned key = S.eq_idx[a]; int q = a - 1;
            while (q >= 0 && S.eq_idx[q] > key) { S.eq_idx[q + 1] = S.eq_idx[q]; --q; }
            S.eq_idx[q + 1] = key;
        }
    }
    __syncthreads();

    // fixup: candidates NOT in the top-k set are out-set -> subtract 0.4x
    for (int ci = tid; ci < cc; ci += 512) {
        unsigned key = S.candKey[ci], idx = S.candIdx[ci];
        bool inset;
        if (key > thr) inset = true;
        else if (key < thr) inset = false;
        else {
            unsigned rank = 0;
            for (int e = 0; e < ecnt; ++e) rank += (S.eq_idx[e] < idx);
            inset = (rank < need_eq);
        }
        if (!inset) {
            int y = (int)(idx >> 7), xx = (int)(idx & 127);
            atomicAdd(&S.pooled_s[(y >> 3) * 16 + (xx >> 3)], -0.4f * xrow[idx]);
        }
    }
    __syncthreads();

    if (tid < 256) {
        float s = S.pooled_s[tid] * (1.0f / 64.0f);
        float pv = s > 0.f ? s : 0.01f * s;
        pooled[(size_t)row * NWIN + tid] = pv;
    }
}

// ---------------------------------------------------------------------------
// MEGA2: {k3 qkv MFMA} ids [0,3072) XCD-aware; {k2 windows} ids [3072,3584).
// ---------------------------------------------------------------------------
template <bool FAST>
__global__ __launch_bounds__(256) void mega2(const float* __restrict__ x,
                                             const unsigned short* __restrict__ xt,
                                             const unsigned short* __restrict__ wq,
                                             const float* __restrict__ qkv_b,
                                             unsigned short* __restrict__ qb,
                                             unsigned short* __restrict__ kb,
                                             unsigned short* __restrict__ vb,
                                             const float* __restrict__ pooled,
                                             const float* __restrict__ bias_w,
                                             const float* __restrict__ bias_b,
                                             const float* __restrict__ scale_w,
                                             const float* __restrict__ scale_b,
                                             float* __restrict__ sb) {
    constexpr int BN = 128, KC = 64, KCP = 72;
    __shared__ unsigned short Ws[CCH][KCP];
    __shared__ unsigned short Xt[BN][KCP];
    int id = blockIdx.x;
    int tid = threadIdx.x;

    if (id >= 3072) {
        int g = id - 3072;
        float* pcol = (float*)&Ws[0][0];
        float* res = pcol + 4 * CCH;
        int wv = tid >> 6, lane = tid & 63;
        int blk = g * 4 + wv;
        int b = blk >> 8, w = blk & 255;
        for (int c = lane; c < CCH; c += 64) pcol[wv * CCH + c] = pooled[(size_t)(b * CCH + c) * NWIN + w];
        __syncthreads();
        if (lane < 24) {
            bool isScale = lane >= 12;
            int o = isScale ? lane - 12 : lane;
            const float* Wt = isScale ? scale_w : bias_w;
            float acc = 0.f;
            for (int c = 0; c < CCH; ++c) acc += Wt[o * CCH + c] * pcol[wv * CCH + c];
            acc += (isScale ? scale_b[o] : bias_b[o]);
            if (!isScale) acc *= (1.0f / 16.0f);
            res[wv * 24 + lane] = acc;
        }
        __syncthreads();
        if (lane < NH) {
            int p = b * NH + lane;
            float4 v;
            v.x = res[wv * 24 + 12 + 2 * lane];
            v.y = res[wv * 24 + 12 + 2 * lane + 1];
            v.z = res[wv * 24 + 2 * lane];
            v.w = res[wv * 24 + 2 * lane + 1];
            ((float4*)sb)[(size_t)p * NWIN + w] = v;
        }
        return;
    }

    int K = id;
    int grp = K / 24, within = K % 24;
    int t = within >> 3, slot = within & 7;
    int tile = grp * 8 + slot;
    int b = tile >> 7;
    int px0 = (tile & 127) * BN;
    int o0 = t * CCH;
    int wv = tid >> 6, lane = tid & 63, lr = lane & 15, lg = lane >> 4;

    f32x4 acc[3][8];
#pragma unroll
    for (int i = 0; i < 3; ++i)
#pragma unroll
        for (int j = 0; j < 8; ++j) acc[i][j] = (f32x4){0.f, 0.f, 0.f, 0.f};

    int spx = tid & 127, skg = tid >> 7;

    for (int k0 = 0; k0 < CCH; k0 += KC) {
#pragma unroll
        for (int i = 0; i < 6; ++i) {
            int u = tid + 256 * i;
            int o = u >> 3, kb8 = u & 7;
            *(u16x8*)&Ws[o][kb8 * 8] = *(const u16x8*)&wq[(size_t)(o0 + o) * CCH + k0 + kb8 * 8];
        }
        if (FAST) {
#pragma unroll
            for (int i = 0; i < 4; ++i) {
                int u = tid + 256 * i;
                int px = u >> 3, kb8 = u & 7;
                *(u16x8*)&Xt[px][kb8 * 8] =
                    *(const u16x8*)&xt[((size_t)(b * NPIX) + px0 + px) * CCH + k0 + kb8 * 8];
            }
        } else {
            const float* xcol = &x[(size_t)(b * CCH + k0 + skg * 32) * NPIX + px0 + spx];
#pragma unroll
            for (int j8 = 0; j8 < 4; ++j8) {
                u16x8 pk;
#pragma unroll
                for (int j = 0; j < 8; ++j) pk[j] = f2bf(xcol[(size_t)(j8 * 8 + j) * NPIX]);
                *(u16x8*)&Xt[spx][skg * 32 + j8 * 8] = pk;
            }
        }
        __syncthreads();
#pragma unroll
        for (int kk = 0; kk < KC; kk += 32) {
            bf16x8 af[3], bfr[8];
#pragma unroll
            for (int i = 0; i < 3; ++i)
                af[i] = *(const bf16x8*)&Ws[wv * 48 + i * 16 + lr][kk + lg * 8];
#pragma unroll
            for (int j = 0; j < 8; ++j)
                bfr[j] = *(const bf16x8*)&Xt[j * 16 + lr][kk + lg * 8];
#pragma unroll
            for (int i = 0; i < 3; ++i)
#pragma unroll
                for (int j = 0; j < 8; ++j)
                    acc[i][j] = __builtin_amdgcn_mfma_f32_16x16x32_bf16(af[i], bfr[j], acc[i][j], 0, 0, 0);
        }
        __syncthreads();
    }

#pragma unroll
    for (int i = 0; i < 3; ++i) {
        int och = wv * 48 + i * 16 + lg * 4;
        float b0 = qkv_b[o0 + och], b1 = qkv_b[o0 + och + 1];
        float b2 = qkv_b[o0 + och + 2], b3 = qkv_b[o0 + och + 3];
#pragma unroll
        for (int j = 0; j < 8; ++j) {
            int px = px0 + lr + j * 16;
            u16x4 pk = { f2bf(acc[i][j][0] + b0), f2bf(acc[i][j][1] + b1),
                         f2bf(acc[i][j][2] + b2), f2bf(acc[i][j][3] + b3) };
            if (t == 0) {
                *(u16x4*)&qb[((size_t)b * NPIX + px) * CCH + och] = pk;
            } else {
                int head = och >> 5, d = och & 31;
                unsigned short* dst = (t == 1) ? kb : vb;
                *(u16x4*)&dst[(((size_t)(b * NH + head)) * NPIX + px) * HDIM + d] = pk;
            }
        }
    }
}

// ---------------------------------------------------------------------------
// K4: wave-per-window MFMA attention (round-14 proven version, Pl in LDS).
// ---------------------------------------------------------------------------
__global__ __launch_bounds__(256) void k4_attn(unsigned short* __restrict__ qatt,
                                               const unsigned short* __restrict__ kb,
                                               const unsigned short* __restrict__ vb,
                                               const float* __restrict__ sb,
                                               const float* __restrict__ rel_table) {
    int tid = threadIdx.x;
    int wv = tid >> 6, lane = tid & 63, lr = lane & 15, lg = lane >> 4;
    int head = blockIdx.y, b = blockIdx.z;
    int win = blockIdx.x * 4 + wv;
    int wy = win >> 4, wx = win & 15;
    int p = b * NH + head;

    __shared__ float rel_s[225];
    __shared__ unsigned short Vl[4][64][33];
    __shared__ unsigned short Pl[4][64][68];

    if (tid < 225) rel_s[tid] = rel_table[tid * NH + head];

    bf16x8 qf[4];
#pragma unroll
    for (int tq = 0; tq < 4; ++tq) {
        int q = tq * 16 + lr;
        int pix = (wy * 8 + (q >> 3)) * IW + wx * 8 + (q & 7);
        qf[tq] = *(const bf16x8*)&qatt[((size_t)b * NPIX + pix) * CCH + head * HDIM + lg * 8];
    }

    float4 sbv = ((const float4*)sb)[(size_t)p * NWIN + win];
    bf16x8 kf[4];
#pragma unroll
    for (int mi = 0; mi < 4; ++mi) {
        int px = mi * 16 + lr;
        int dy = px >> 3, dx = px & 7;
        int yg = wy * 8 + dy, xg = wx * 8 + dx;
        float gx = -1.0f + xg * (2.0f / 127.0f) + ((float)dx - 3.5f) * (2.0f / 127.0f) * sbv.x + sbv.z;
        float gy = -1.0f + yg * (2.0f / 127.0f) + ((float)dy - 3.5f) * (2.0f / 127.0f) * sbv.y + sbv.w;
        float fx = (gx + 1.0f) * 0.5f * 127.0f;
        float fy = (gy + 1.0f) * 0.5f * 127.0f;
        float x0f = floorf(fx), y0f = floorf(fy);
        float wx1 = fx - x0f, wy1 = fy - y0f;
        int ix0 = (int)x0f, iy0 = (int)y0f;
        int ix1 = ix0 + 1, iy1 = iy0 + 1;
        float w00 = (1.0f - wx1) * (1.0f - wy1);
        float w10 = wx1 * (1.0f - wy1);
        float w01 = (1.0f - wx1) * wy1;
        float w11 = wx1 * wy1;
        bool vX0 = (ix0 >= 0) && (ix0 < IW), vX1 = (ix1 >= 0) && (ix1 < IW);
        bool vY0 = (iy0 >= 0) && (iy0 < IH), vY1 = (iy1 >= 0) && (iy1 < IH);
        if (!(vX0 && vY0)) w00 = 0.f;
        if (!(vX1 && vY0)) w10 = 0.f;
        if (!(vX0 && vY1)) w01 = 0.f;
        if (!(vX1 && vY1)) w11 = 0.f;
        int cx0 = min(max(ix0, 0), IW - 1), cx1 = min(max(ix1, 0), IW - 1);
        int cy0 = min(max(iy0, 0), IH - 1), cy1 = min(max(iy1, 0), IH - 1);
        size_t r00 = ((size_t)p * NPIX + cy0 * IW + cx0) * HDIM + lg * 8;
        size_t r10 = ((size_t)p * NPIX + cy0 * IW + cx1) * HDIM + lg * 8;
        size_t r01 = ((size_t)p * NPIX + cy1 * IW + cx0) * HDIM + lg * 8;
        size_t r11 = ((size_t)p * NPIX + cy1 * IW + cx1) * HDIM + lg * 8;
        u16x8 k00 = *(const u16x8*)&kb[r00], k10 = *(const u16x8*)&kb[r10];
        u16x8 k01 = *(const u16x8*)&kb[r01], k11 = *(const u16x8*)&kb[r11];
        u16x8 v00 = *(const u16x8*)&vb[r00], v10 = *(const u16x8*)&vb[r10];
        u16x8 v01 = *(const u16x8*)&vb[r01], v11 = *(const u16x8*)&vb[r11];
#pragma unroll
        for (int c = 0; c < 8; ++c) {
            float kvv = w00 * bf2f(k00[c]) + w10 * bf2f(k10[c]) +
                        w01 * bf2f(k01[c]) + w11 * bf2f(k11[c]);
            float vvv = w00 * bf2f(v00[c]) + w10 * bf2f(v10[c]) +
                        w01 * bf2f(v01[c]) + w11 * bf2f(v11[c]);
            kf[mi][c] = (short)f2bf(kvv);
            Vl[wv][px][lg * 8 + c] = f2bf(vvv);
        }
    }

    f32x4 acc[4][4];
#pragma unroll
    for (int tk = 0; tk < 4; ++tk)
#pragma unroll
        for (int tq = 0; tq < 4; ++tq) acc[tk][tq] = (f32x4){0.f, 0.f, 0.f, 0.f};
#pragma unroll
    for (int tk = 0; tk < 4; ++tk)
#pragma unroll
        for (int tq = 0; tq < 4; ++tq)
            acc[tk][tq] = __builtin_amdgcn_mfma_f32_16x16x32_bf16(kf[tk], qf[tq], acc[tk][tq], 0, 0, 0);

    __syncthreads();

    const float scale = 0.17677669529663688f;
    int qh[4], qwv[4];
#pragma unroll
    for (int tq = 0; tq < 4; ++tq) { int q = tq * 16 + lr; qh[tq] = q >> 3; qwv[tq] = q & 7; }
    float mx[4] = {-1e30f, -1e30f, -1e30f, -1e30f};
#pragma unroll
    for (int tk = 0; tk < 4; ++tk)
#pragma unroll
        for (int r = 0; r < 4; ++r) {
            int key = tk * 16 + lg * 4 + r;
            int kh = key >> 3, kw = key & 7;
#pragma unroll
            for (int tq = 0; tq < 4; ++tq) {
                float v = acc[tk][tq][r] * scale + rel_s[(qh[tq] - kh + 7) * 15 + (qwv[tq] - kw + 7)];
                acc[tk][tq][r] = v;
                mx[tq] = fmaxf(mx[tq], v);
            }
        }
#pragma unroll
    for (int tq = 0; tq < 4; ++tq) {
        mx[tq] = fmaxf(mx[tq], __shfl_xor(mx[tq], 16));
        mx[tq] = fmaxf(mx[tq], __shfl_xor(mx[tq], 32));
    }
    float sm[4] = {0.f, 0.f, 0.f, 0.f};
#pragma unroll
    for (int tk = 0; tk < 4; ++tk)
#pragma unroll
        for (int tq = 0; tq < 4; ++tq)
#pragma unroll
            for (int r = 0; r < 4; ++r) {
                float e = __expf(acc[tk][tq][r] - mx[tq]);
                acc[tk][tq][r] = e;
                sm[tq] += e;
            }
    float inv[4];
#pragma unroll
    for (int tq = 0; tq < 4; ++tq) {
        float s = sm[tq];
        s += __shfl_xor(s, 16);
        s += __shfl_xor(s, 32);
        inv[tq] = 1.0f / s;
    }
#pragma unroll
    for (int tq = 0; tq < 4; ++tq)
#pragma unroll
        for (int tk = 0; tk < 4; ++tk) {
            u16x4 pk = { f2bf(acc[tk][tq][0] * inv[tq]), f2bf(acc[tk][tq][1] * inv[tq]),
                         f2bf(acc[tk][tq][2] * inv[tq]), f2bf(acc[tk][tq][3] * inv[tq]) };
            *(u16x4*)&Pl[wv][tq * 16 + lr][tk * 16 + lg * 4] = pk;
        }

    __syncthreads();

    f32x4 o[4][2];
#pragma unroll
    for (int mq = 0; mq < 4; ++mq)
#pragma unroll
        for (int nd = 0; nd < 2; ++nd) o[mq][nd] = (f32x4){0.f, 0.f, 0.f, 0.f};
#pragma unroll
    for (int ks = 0; ks < 2; ++ks) {
        bf16x8 Af[4];
#pragma unroll
        for (int mq = 0; mq < 4; ++mq) {
            u16x4 lo = *(const u16x4*)&Pl[wv][mq * 16 + lr][ks * 32 + lg * 8];
            u16x4 hi = *(const u16x4*)&Pl[wv][mq * 16 + lr][ks * 32 + lg * 8 + 4];
#pragma unroll
            for (int c = 0; c < 4; ++c) { Af[mq][c] = (short)lo[c]; Af[mq][c + 4] = (short)hi[c]; }
        }
        bf16x8 Bf[2];
#pragma unroll
        for (int nd = 0; nd < 2; ++nd)
#pragma unroll
            for (int j = 0; j < 8; ++j)
                Bf[nd][j] = (short)Vl[wv][ks * 32 + lg * 8 + j][nd * 16 + lr];
#pragma unroll
        for (int mq = 0; mq < 4; ++mq)
#pragma unroll
            for (int nd = 0; nd < 2; ++nd)
                o[mq][nd] = __builtin_amdgcn_mfma_f32_16x16x32_bf16(Af[mq], Bf[nd], o[mq][nd], 0, 0, 0);
    }

#pragma unroll
    for (int mq = 0; mq < 4; ++mq)
#pragma unroll
        for (int nd = 0; nd < 2; ++nd)
#pragma unroll
            for (int r = 0; r < 4; ++r) {
                int q = mq * 16 + lg * 4 + r;
                int pix = (wy * 8 + (q >> 3)) * IW + wx * 8 + (q & 7);
                qatt[((size_t)b * NPIX + pix) * CCH + head * HDIM + nd * 16 + lr] = f2bf(o[mq][nd][r]);
            }
}

// ---------------------------------------------------------------------------
// K5: projection via bf16 MFMA (W from bf16 wp).
// ---------------------------------------------------------------------------
__global__ __launch_bounds__(256) void k5_mfma(const unsigned short* __restrict__ att,
                                               const unsigned short* __restrict__ wp,
                                               const float* __restrict__ proj_b,
                                               float* __restrict__ out) {
    constexpr int BN = 128, KC = 64, KCP = 72;
    __shared__ unsigned short Ws[CCH][KCP];
    __shared__ unsigned short Xt[BN][KCP];
    int px0 = blockIdx.x * BN;
    int b = blockIdx.y;
    int tid = threadIdx.x;
    int wv = tid >> 6, lane = tid & 63, lr = lane & 15, lg = lane >> 4;

    f32x4 acc[3][8];
#pragma unroll
    for (int i = 0; i < 3; ++i)
#pragma unroll
        for (int j = 0; j < 8; ++j) acc[i][j] = (f32x4){0.f, 0.f, 0.f, 0.f};

    int spx = tid & 127, skg = tid >> 7;

    for (int k0 = 0; k0 < CCH; k0 += KC) {
#pragma unroll
        for (int i = 0; i < 6; ++i) {
            int u = tid + 256 * i;
            int o = u >> 3, kb8 = u & 7;
            *(u16x8*)&Ws[o][kb8 * 8] = *(const u16x8*)&wp[(size_t)o * CCH + k0 + kb8 * 8];
        }
        {
            const unsigned short* arow = &att[((size_t)b * NPIX + px0 + spx) * CCH + k0 + skg * 32];
#pragma unroll
            for (int j8 = 0; j8 < 4; ++j8)
                *(u16x8*)&Xt[spx][skg * 32 + j8 * 8] = *(const u16x8*)&arow[j8 * 8];
        }
        __syncthreads();
#pragma unroll
        for (int kk = 0; kk < KC; kk += 32) {
            bf16x8 af[3], bfr[8];
#pragma unroll
            for (int i = 0; i < 3; ++i)
                af[i] = *(const bf16x8*)&Ws[wv * 48 + i * 16 + lr][kk + lg * 8];
#pragma unroll
            for (int j = 0; j < 8; ++j)
                bfr[j] = *(const bf16x8*)&Xt[j * 16 + lr][kk + lg * 8];
#pragma unroll
            for (int i = 0; i < 3; ++i)
#pragma unroll
                for (int j = 0; j < 8; ++j)
                    acc[i][j] = __builtin_amdgcn_mfma_f32_16x16x32_bf16(af[i], bfr[j], acc[i][j], 0, 0, 0);
        }
        __syncthreads();
    }

#pragma unroll
    for (int i = 0; i < 3; ++i) {
        int och = wv * 48 + i * 16 + lg * 4;
#pragma unroll
        for (int r = 0; r < 4; ++r) {
            float bias = proj_b[och + r];
            size_t base = (size_t)(b * CCH + och + r) * NPIX + px0 + lr;
#pragma unroll
            for (int j = 0; j < 8; ++j)
                out[base + j * 16] = acc[i][j][r] + bias;
        }
    }
}

// ---------------------------------------------------------------------------
extern "C" void kernel_launch(void* const* d_in, const int* in_sizes, int n_in,
                              void* d_out, int out_size, void* d_ws, size_t ws_size,
                              hipStream_t stream) {
    const float* x = (const float*)d_in[0];
    const float* var = (const float*)d_in[1];
    const float* qkv_w = (const float*)d_in[2];
    const float* qkv_b = (const float*)d_in[3];
    const float* bias_w = (const float*)d_in[4];
    const float* bias_b = (const float*)d_in[5];
    const float* scale_w = (const float*)d_in[6];
    const float* scale_b = (const float*)d_in[7];
    const float* proj_w = (const float*)d_in[8];
    const float* proj_b = (const float*)d_in[9];
    const float* rel_table = (const float*)d_in[10];
    float* out = (float*)d_out;

    char* ws = (char*)d_ws;
    float* pooled = (float*)ws;                           // 1,572,864 B
    float* sb = (float*)(ws + 1572864ull);                // 196,608 B
    const size_t elemQ = (size_t)BB * CCH * NPIX;         // 25,165,824
    unsigned short* q = (unsigned short*)(ws + 1769472ull);
    unsigned short* k = q + elemQ;
    unsigned short* v = k + elemQ;
    unsigned short* wbf = v + elemQ;                      // 147,456 u16
    unsigned short* wq_bf = wbf;
    unsigned short* wp_bf = wbf + 110592;
    unsigned short* xt = wbf + 147456;

    size_t need_base = 1769472ull + 3ull * elemQ * 2 + 294912ull;
    size_t need_fast = need_base + elemQ * 2;
    if (ws_size < need_base) return;
    bool fast = ws_size >= need_fast;

    mega1<<<dim3(72 + (fast ? 3584 : 1536)), dim3(512), 0, stream>>>(
        x, var, pooled, xt, qkv_w, proj_w, wbf, fast ? 1 : 0);

    if (fast) {
        mega2<true><<<dim3(3584), dim3(256), 0, stream>>>(x, xt, wq_bf, qkv_b, q, k, v,
                                                          pooled, bias_w, bias_b, scale_w, scale_b, sb);
    } else {
        mega2<false><<<dim3(3584), dim3(256), 0, stream>>>(x, xt, wq_bf, qkv_b, q, k, v,
                                                           pooled, bias_w, bias_b, scale_w, scale_b, sb);
    }

    k4_attn<<<dim3(NWIN / 4, NH, BB), dim3(256), 0, stream>>>(q, k, v, sb, rel_table);
    k5_mfma<<<dim3(NPIX / 128, BB), dim3(256), 0, stream>>>(q, wp_bf, proj_b, out);
}

// Round 18
// 266.876 us; speedup vs baseline: 1.1613x; 1.1613x over previous
//
#include <hip/hip_runtime.h>
#include <hip/hip_bf16.h>
#include <math.h>

constexpr int BB = 8, CCH = 192, IH = 128, IW = 128;
constexpr int WSZ = 8;
constexpr int NWIN = 256;
constexpr int NH = 6, HDIM = 32;
constexpr int NPIX = IH * IW;
constexpr int TOPK = 13107;

typedef __attribute__((ext_vector_type(8))) short bf16x8;
typedef __attribute__((ext_vector_type(4))) float f32x4;
typedef __attribute__((ext_vector_type(4))) unsigned short u16x4;
typedef __attribute__((ext_vector_type(8))) unsigned short u16x8;

__device__ __forceinline__ unsigned short f2bf(float f) {
    __hip_bfloat16 h = __float2bfloat16(f);
    return __builtin_bit_cast(unsigned short, h);
}
__device__ __forceinline__ float bf2f(unsigned short u) {
    return __uint_as_float((unsigned)u << 16);
}
__device__ __forceinline__ unsigned monot(float f) {
    unsigned u = __float_as_uint(f);
    return (u & 0x80000000u) ? ~u : (u | 0x80000000u);
}

// ---------------------------------------------------------------------------
// MEGA1: role-fused launch: {kw weight bf16 convert} + {k1 top-k pool rows}
//        || {k0x transpose tiles}. Block = 512 threads.
// ---------------------------------------------------------------------------
struct K1Smem {
    unsigned histP[2][2048];
    unsigned hist256[256];
    unsigned wtot[8];
    unsigned s_prefix, s_rem, s_cnt, s_thr, s_need;
    unsigned candKey[320], candIdx[320];
    unsigned cand_cnt, eq_cnt;
    unsigned eq_idx[64];
    float pooled_s[256];
};
struct K0Smem {
    unsigned short T[64][200];
};
constexpr size_t MEGA1_SMEM = sizeof(K0Smem) > sizeof(K1Smem) ? sizeof(K0Smem) : sizeof(K1Smem);

__global__ __launch_bounds__(512) void mega1(const float* __restrict__ x,
                                             const float* __restrict__ var,
                                             float* __restrict__ pooled,
                                             unsigned short* __restrict__ xt,
                                             const float* __restrict__ qkv_w,
                                             const float* __restrict__ proj_w,
                                             unsigned short* __restrict__ wbf,
                                             int fast) {
    __shared__ __align__(16) char smem[MEGA1_SMEM];
    int id = blockIdx.x;
    int tid = threadIdx.x;
    int wv = tid >> 6, lane = tid & 63;

    if (id < 72) {
        // ---- kw: convert qkv_w + proj_w to bf16 ----
        int i4 = id * 512 + tid;     // [0, 36864)
        float4 v = (i4 < 27648) ? ((const float4*)qkv_w)[i4]
                                : ((const float4*)proj_w)[i4 - 27648];
        u16x4 pk = { f2bf(v.x), f2bf(v.y), f2bf(v.z), f2bf(v.w) };
        ((u16x4*)wbf)[i4] = pk;
        return;
    }
    id -= 72;

    int role, sub;
    if (fast) {
        int g = id / 7, r = id % 7;
        if (r < 3) { role = 0; sub = 3 * g + r; }
        else       { role = 1; sub = 4 * g + (r - 3); }
    } else {
        role = 0; sub = id;
    }

    if (role == 1) {
        // ---- k0x: transpose one 64-px tile to channel-last bf16 ----
        K0Smem& S0 = *(K0Smem*)smem;
        int b = sub >> 8, px0 = (sub & 255) * 64;
        int px = tid & 63, cg = tid >> 6;
#pragma unroll
        for (int j8 = 0; j8 < 3; ++j8) {
            u16x8 pk;
#pragma unroll
            for (int j = 0; j < 8; ++j)
                pk[j] = f2bf(x[(size_t)(b * CCH + cg * 24 + j8 * 8 + j) * NPIX + px0 + px]);
            *(u16x8*)&S0.T[px][cg * 24 + j8 * 8] = pk;
        }
        __syncthreads();
#pragma unroll
        for (int i = 0; i < 3; ++i) {
            int u = tid + 512 * i;
            int p2 = u / 24, cb = u % 24;
            *(u16x8*)&xt[((size_t)(b * NPIX) + px0 + p2) * CCH + cb * 8] = *(const u16x8*)&S0.T[p2][cb * 8];
        }
        return;
    }

    // ---- k1: exact top-k threshold + masked pool (proven round-13 version) ----
    K1Smem& S = *(K1Smem*)smem;
    int row = sub;
    const float4* vrow4 = (const float4*)(var + (size_t)row * NPIX);
    const float4* xrow4 = (const float4*)(x + (size_t)row * NPIX);
    const float* xrow = x + (size_t)row * NPIX;
    constexpr int CAP = 320;

    for (int i = tid; i < 2 * 2048; i += 512) ((unsigned*)S.histP)[i] = 0;
    if (tid < 256) S.pooled_s[tid] = 0.f;
    if (tid == 0) { S.cand_cnt = 0; S.eq_cnt = 0; }
    __syncthreads();

    // sweep 1: 12-bit histogram (packed u16 halves)
    int hc = lane & 1;
#pragma unroll
    for (int j = 0; j < 8; ++j) {
        float4 v4 = vrow4[tid + 512 * j];
        float vv[4] = {v4.x, v4.y, v4.z, v4.w};
#pragma unroll
        for (int c = 0; c < 4; ++c) {
            unsigned bk = monot(vv[c]) >> 20;
            atomicAdd(&S.histP[hc][bk >> 1], 1u << ((bk & 1) << 4));
        }
    }
    __syncthreads();

    // scan 4096 buckets: thread owns [8*tid, 8*tid+7]
    {
        unsigned h8[8]; unsigned tsum = 0;
#pragma unroll
        for (int w = 0; w < 4; ++w) {
            unsigned w0 = S.histP[0][tid * 4 + w];
            unsigned w1 = S.histP[1][tid * 4 + w];
            h8[2 * w]     = (w0 & 0xFFFFu) + (w1 & 0xFFFFu);
            h8[2 * w + 1] = (w0 >> 16) + (w1 >> 16);
            tsum += h8[2 * w] + h8[2 * w + 1];
        }
        unsigned s = tsum;
#pragma unroll
        for (int off = 1; off < 64; off <<= 1) {
            unsigned t = __shfl(s, lane + off);
            if (lane + off < 64) s += t;
        }
        if (lane == 0) S.wtot[wv] = s;
        __syncthreads();
        unsigned crossTot = 0;
        for (int w = wv + 1; w < 8; ++w) crossTot += S.wtot[w];
        unsigned above = crossTot + (s - tsum);
        if (above < TOPK && above + tsum >= TOPK) {
            unsigned cum = above;
            for (int i = 7; i >= 0; --i) {
                if (cum < TOPK && cum + h8[i] >= TOPK) {
                    S.s_prefix = (unsigned)(tid * 8 + i);
                    S.s_rem = TOPK - cum;
                    S.s_cnt = h8[i];
                }
                cum += h8[i];
            }
        }
    }
    __syncthreads();

    unsigned prefix = S.s_prefix, rem2 = S.s_rem, cnt = S.s_cnt;
    int prefbits = 12;

    // fallback refinement (normally 0 iterations)
    while (cnt > CAP && prefbits < 32) {
        int nb = (32 - prefbits >= 8) ? 8 : (32 - prefbits);
        int nbuck = 1 << nb;
        __syncthreads();
        for (int i = tid; i < nbuck; i += 512) S.hist256[i] = 0;
        __syncthreads();
        int shift = 32 - prefbits - nb;
#pragma unroll
        for (int j = 0; j < 8; ++j) {
            float4 v4 = vrow4[tid + 512 * j];
            float vv[4] = {v4.x, v4.y, v4.z, v4.w};
#pragma unroll
            for (int c = 0; c < 4; ++c) {
                unsigned mm = monot(vv[c]);
                if ((mm >> (nb + shift)) == prefix)
                    atomicAdd(&S.hist256[(mm >> shift) & (nbuck - 1)], 1u);
            }
        }
        __syncthreads();
        if (wv == 0) {
            int bpl = nbuck > 64 ? nbuck / 64 : 1;
            int nlanes = nbuck / bpl;
            unsigned hh[4] = {0, 0, 0, 0};
            unsigned lsum = 0;
#pragma unroll
            for (int i = 0; i < 4; ++i) {
                if (i < bpl && lane < nlanes) hh[i] = S.hist256[lane * bpl + i];
                lsum += hh[i];
            }
            unsigned s = lsum;
#pragma unroll
            for (int off = 1; off < 64; off <<= 1) {
                unsigned t = __shfl(s, lane + off);
                if (lane + off < 64) s += t;
            }
            unsigned above = s - lsum;
            if (lane < nlanes && above < rem2 && above + lsum >= rem2) {
                unsigned cum = above;
                for (int i = bpl - 1; i >= 0; --i) {
                    if (cum < rem2 && cum + hh[i] >= rem2) {
                        S.s_prefix = (prefix << nb) | (unsigned)(lane * bpl + i);
                        S.s_rem = rem2 - cum;
                        S.s_cnt = hh[i];
                    }
                    cum += hh[i];
                }
            }
        }
        __syncthreads();
        prefix = S.s_prefix; rem2 = S.s_rem; cnt = S.s_cnt;
        prefbits += nb;
    }

    int pshift = 32 - prefbits;

    // sweep 2 (fused): provisional pooling + candidate collection
#pragma unroll
    for (int j = 0; j < 8; ++j) {
        float4 v4 = vrow4[tid + 512 * j];
        float4 x4 = xrow4[tid + 512 * j];
        float vv[4] = {v4.x, v4.y, v4.z, v4.w};
        float xv[4] = {x4.x, x4.y, x4.z, x4.w};
        float part = 0.f;
#pragma unroll
        for (int c = 0; c < 4; ++c) {
            unsigned mm = monot(vv[c]);
            unsigned g = (pshift == 0) ? mm : (mm >> pshift);
            float mult = (g > prefix) ? 1.0f : 0.6f;
            if (g == prefix) {
                unsigned pos = atomicAdd(&S.cand_cnt, 1u);
                if (pos < CAP) {
                    S.candKey[pos] = mm;
                    S.candIdx[pos] = (unsigned)(4 * tid + 2048 * j + c);
                }
            }
            part += xv[c] * mult;
        }
        part += __shfl_xor(part, 1);
        part += __shfl_xor(part, 32);
        if ((lane & 1) == 0 && lane < 32)
            atomicAdd(&S.pooled_s[(2 * j + (tid >> 8)) * 16 + ((tid >> 1) & 15)], part);
    }
    __syncthreads();

    // exact threshold among candidates (rank via LDS broadcast)
    int cc = (int)min(S.cand_cnt, (unsigned)CAP);
    for (int ci = tid; ci < cc; ci += 512) {
        unsigned my = S.candKey[ci];
        unsigned kgt = 0, keq = 0;
        for (int e = 0; e < cc; ++e) {
            unsigned o = S.candKey[e];
            kgt += (o > my);
            keq += (o == my);
        }
        if (kgt < rem2 && kgt + keq >= rem2) {
            S.s_thr = my;
            S.s_need = rem2 - kgt;
        }
    }
    __syncthreads();
    unsigned thr = S.s_thr, need_eq = S.s_need;
    for (int ci = tid; ci < cc; ci += 512)
        if (S.candKey[ci] == thr) {
            unsigned pos = atomicAdd(&S.eq_cnt, 1u);
            if (pos < 64) S.eq_idx[pos] = S.candIdx[ci];
        }
    __syncthreads();
    int ecnt = (int)min(S.eq_cnt, 64u);
    if (tid == 0) {
        for (int a = 1; a < ecnt; ++a) {
            unsigned key = S.eq_idx[a]; int q = a - 1;
            while (q >= 0 && S.eq_idx[q] > key) { S.eq_idx[q + 1] = S.eq_idx[q]; --q; }
            S.eq_idx[q + 1] = key;
        }
    }
    __syncthreads();

    // fixup: in-set candidates were pooled at 0.6 -> add 0.4*x
    for (int ci = tid; ci < cc; ci += 512) {
        unsigned key = S.candKey[ci], idx = S.candIdx[ci];
        bool inset;
        if (key > thr) inset = true;
        else if (key < thr) inset = false;
        else {
            unsigned rank = 0;
            for (int e = 0; e < ecnt; ++e) rank += (S.eq_idx[e] < idx);
            inset = (rank < need_eq);
        }
        if (inset) {
            int y = (int)(idx >> 7), xx = (int)(idx & 127);
            atomicAdd(&S.pooled_s[(y >> 3) * 16 + (xx >> 3)], 0.4f * xrow[idx]);
        }
    }
    __syncthreads();

    if (tid < 256) {
        float s = S.pooled_s[tid] * (1.0f / 64.0f);
        float pv = s > 0.f ? s : 0.01f * s;
        pooled[(size_t)row * NWIN + tid] = pv;
    }
}

// ---------------------------------------------------------------------------
// MEGA2: role-fused {k2 windows} || {k3 qkv MFMA, W from bf16 wbf}. 1:6.
// ---------------------------------------------------------------------------
template <bool FAST>
__global__ __launch_bounds__(256) void mega2(const float* __restrict__ x,
                                             const unsigned short* __restrict__ xt,
                                             const unsigned short* __restrict__ wq,
                                             const float* __restrict__ qkv_b,
                                             unsigned short* __restrict__ qb,
                                             unsigned short* __restrict__ kb,
                                             unsigned short* __restrict__ vb,
                                             const float* __restrict__ pooled,
                                             const float* __restrict__ bias_w,
                                             const float* __restrict__ bias_b,
                                             const float* __restrict__ scale_w,
                                             const float* __restrict__ scale_b,
                                             float* __restrict__ sb) {
    constexpr int BN = 128, KC = 64, KCP = 72;
    __shared__ unsigned short Ws[CCH][KCP];
    __shared__ unsigned short Xt[BN][KCP];
    int id = blockIdx.x;
    int tid = threadIdx.x;
    int g = id / 7, r = id % 7;

    if (r == 0) {
        // ---- k2: 4 windows, one per wave ----
        float* pcol = (float*)&Ws[0][0];
        float* res = pcol + 4 * CCH;
        int wv = tid >> 6, lane = tid & 63;
        int blk = g * 4 + wv;
        int b = blk >> 8, w = blk & 255;
        for (int c = lane; c < CCH; c += 64) pcol[wv * CCH + c] = pooled[(size_t)(b * CCH + c) * NWIN + w];
        __syncthreads();
        if (lane < 24) {
            bool isScale = lane >= 12;
            int o = isScale ? lane - 12 : lane;
            const float* Wt = isScale ? scale_w : bias_w;
            float acc = 0.f;
            for (int c = 0; c < CCH; ++c) acc += Wt[o * CCH + c] * pcol[wv * CCH + c];
            acc += (isScale ? scale_b[o] : bias_b[o]);
            if (!isScale) acc *= (1.0f / 16.0f);
            res[wv * 24 + lane] = acc;
        }
        __syncthreads();
        if (lane < NH) {
            int p = b * NH + lane;
            float4 v;
            v.x = res[wv * 24 + 12 + 2 * lane];
            v.y = res[wv * 24 + 12 + 2 * lane + 1];
            v.z = res[wv * 24 + 2 * lane];
            v.w = res[wv * 24 + 2 * lane + 1];
            ((float4*)sb)[(size_t)p * NWIN + w] = v;
        }
        return;
    }

    // ---- k3: qkv 1x1 conv via bf16 MFMA ----
    int k3id = 6 * g + (r - 1);
    int px0 = (k3id & 127) * BN;
    int t = (k3id >> 7) % 3;
    int b = k3id / 384;
    int o0 = t * CCH;
    int wv = tid >> 6, lane = tid & 63, lr = lane & 15, lg = lane >> 4;

    f32x4 acc[3][8];
#pragma unroll
    for (int i = 0; i < 3; ++i)
#pragma unroll
        for (int j = 0; j < 8; ++j) acc[i][j] = (f32x4){0.f, 0.f, 0.f, 0.f};

    int spx = tid & 127, skg = tid >> 7;

    for (int k0 = 0; k0 < CCH; k0 += KC) {
#pragma unroll
        for (int i = 0; i < 6; ++i) {
            int u = tid + 256 * i;
            int o = u >> 3, kb8 = u & 7;
            *(u16x8*)&Ws[o][kb8 * 8] = *(const u16x8*)&wq[(size_t)(o0 + o) * CCH + k0 + kb8 * 8];
        }
        if (FAST) {
#pragma unroll
            for (int i = 0; i < 4; ++i) {
                int u = tid + 256 * i;
                int px = u >> 3, kb8 = u & 7;
                *(u16x8*)&Xt[px][kb8 * 8] =
                    *(const u16x8*)&xt[((size_t)(b * NPIX) + px0 + px) * CCH + k0 + kb8 * 8];
            }
        } else {
            const float* xcol = &x[(size_t)(b * CCH + k0 + skg * 32) * NPIX + px0 + spx];
#pragma unroll
            for (int j8 = 0; j8 < 4; ++j8) {
                u16x8 pk;
#pragma unroll
                for (int j = 0; j < 8; ++j) pk[j] = f2bf(xcol[(size_t)(j8 * 8 + j) * NPIX]);
                *(u16x8*)&Xt[spx][skg * 32 + j8 * 8] = pk;
            }
        }
        __syncthreads();
#pragma unroll
        for (int kk = 0; kk < KC; kk += 32) {
            bf16x8 af[3], bfr[8];
#pragma unroll
            for (int i = 0; i < 3; ++i)
                af[i] = *(const bf16x8*)&Ws[wv * 48 + i * 16 + lr][kk + lg * 8];
#pragma unroll
            for (int j = 0; j < 8; ++j)
                bfr[j] = *(const bf16x8*)&Xt[j * 16 + lr][kk + lg * 8];
#pragma unroll
            for (int i = 0; i < 3; ++i)
#pragma unroll
                for (int j = 0; j < 8; ++j)
                    acc[i][j] = __builtin_amdgcn_mfma_f32_16x16x32_bf16(af[i], bfr[j], acc[i][j], 0, 0, 0);
        }
        __syncthreads();
    }

#pragma unroll
    for (int i = 0; i < 3; ++i) {
        int och = wv * 48 + i * 16 + lg * 4;
        float b0 = qkv_b[o0 + och], b1 = qkv_b[o0 + och + 1];
        float b2 = qkv_b[o0 + och + 2], b3 = qkv_b[o0 + och + 3];
#pragma unroll
        for (int j = 0; j < 8; ++j) {
            int px = px0 + lr + j * 16;
            u16x4 pk = { f2bf(acc[i][j][0] + b0), f2bf(acc[i][j][1] + b1),
                         f2bf(acc[i][j][2] + b2), f2bf(acc[i][j][3] + b3) };
            if (t == 0) {
                *(u16x4*)&qb[((size_t)b * NPIX + px) * CCH + och] = pk;
            } else {
                int head = och >> 5, d = och & 31;
                unsigned short* dst = (t == 1) ? kb : vb;
                *(u16x4*)&dst[(((size_t)(b * NH + head)) * NPIX + px) * HDIM + d] = pk;
            }
        }
    }
}

// ---------------------------------------------------------------------------
// K4: wave-per-window MFMA attention (round-14 proven version, Pl in LDS).
// ---------------------------------------------------------------------------
__global__ __launch_bounds__(256) void k4_attn(unsigned short* __restrict__ qatt,
                                               const unsigned short* __restrict__ kb,
                                               const unsigned short* __restrict__ vb,
                                               const float* __restrict__ sb,
                                               const float* __restrict__ rel_table) {
    int tid = threadIdx.x;
    int wv = tid >> 6, lane = tid & 63, lr = lane & 15, lg = lane >> 4;
    int head = blockIdx.y, b = blockIdx.z;
    int win = blockIdx.x * 4 + wv;
    int wy = win >> 4, wx = win & 15;
    int p = b * NH + head;

    __shared__ float rel_s[225];
    __shared__ unsigned short Vl[4][64][33];
    __shared__ unsigned short Pl[4][64][68];

    if (tid < 225) rel_s[tid] = rel_table[tid * NH + head];

    bf16x8 qf[4];
#pragma unroll
    for (int tq = 0; tq < 4; ++tq) {
        int q = tq * 16 + lr;
        int pix = (wy * 8 + (q >> 3)) * IW + wx * 8 + (q & 7);
        qf[tq] = *(const bf16x8*)&qatt[((size_t)b * NPIX + pix) * CCH + head * HDIM + lg * 8];
    }

    float4 sbv = ((const float4*)sb)[(size_t)p * NWIN + win];
    bf16x8 kf[4];
#pragma unroll
    for (int mi = 0; mi < 4; ++mi) {
        int px = mi * 16 + lr;
        int dy = px >> 3, dx = px & 7;
        int yg = wy * 8 + dy, xg = wx * 8 + dx;
        float gx = -1.0f + xg * (2.0f / 127.0f) + ((float)dx - 3.5f) * (2.0f / 127.0f) * sbv.x + sbv.z;
        float gy = -1.0f + yg * (2.0f / 127.0f) + ((float)dy - 3.5f) * (2.0f / 127.0f) * sbv.y + sbv.w;
        float fx = (gx + 1.0f) * 0.5f * 127.0f;
        float fy = (gy + 1.0f) * 0.5f * 127.0f;
        float x0f = floorf(fx), y0f = floorf(fy);
        float wx1 = fx - x0f, wy1 = fy - y0f;
        int ix0 = (int)x0f, iy0 = (int)y0f;
        int ix1 = ix0 + 1, iy1 = iy0 + 1;
        float w00 = (1.0f - wx1) * (1.0f - wy1);
        float w10 = wx1 * (1.0f - wy1);
        float w01 = (1.0f - wx1) * wy1;
        float w11 = wx1 * wy1;
        bool vX0 = (ix0 >= 0) && (ix0 < IW), vX1 = (ix1 >= 0) && (ix1 < IW);
        bool vY0 = (iy0 >= 0) && (iy0 < IH), vY1 = (iy1 >= 0) && (iy1 < IH);
        if (!(vX0 && vY0)) w00 = 0.f;
        if (!(vX1 && vY0)) w10 = 0.f;
        if (!(vX0 && vY1)) w01 = 0.f;
        if (!(vX1 && vY1)) w11 = 0.f;
        int cx0 = min(max(ix0, 0), IW - 1), cx1 = min(max(ix1, 0), IW - 1);
        int cy0 = min(max(iy0, 0), IH - 1), cy1 = min(max(iy1, 0), IH - 1);
        size_t r00 = ((size_t)p * NPIX + cy0 * IW + cx0) * HDIM + lg * 8;
        size_t r10 = ((size_t)p * NPIX + cy0 * IW + cx1) * HDIM + lg * 8;
        size_t r01 = ((size_t)p * NPIX + cy1 * IW + cx0) * HDIM + lg * 8;
        size_t r11 = ((size_t)p * NPIX + cy1 * IW + cx1) * HDIM + lg * 8;
        u16x8 k00 = *(const u16x8*)&kb[r00], k10 = *(const u16x8*)&kb[r10];
        u16x8 k01 = *(const u16x8*)&kb[r01], k11 = *(const u16x8*)&kb[r11];
        u16x8 v00 = *(const u16x8*)&vb[r00], v10 = *(const u16x8*)&vb[r10];
        u16x8 v01 = *(const u16x8*)&vb[r01], v11 = *(const u16x8*)&vb[r11];
#pragma unroll
        for (int c = 0; c < 8; ++c) {
            float kvv = w00 * bf2f(k00[c]) + w10 * bf2f(k10[c]) +
                        w01 * bf2f(k01[c]) + w11 * bf2f(k11[c]);
            float vvv = w00 * bf2f(v00[c]) + w10 * bf2f(v10[c]) +
                        w01 * bf2f(v01[c]) + w11 * bf2f(v11[c]);
            kf[mi][c] = (short)f2bf(kvv);
            Vl[wv][px][lg * 8 + c] = f2bf(vvv);
        }
    }

    f32x4 acc[4][4];
#pragma unroll
    for (int tk = 0; tk < 4; ++tk)
#pragma unroll
        for (int tq = 0; tq < 4; ++tq) acc[tk][tq] = (f32x4){0.f, 0.f, 0.f, 0.f};
#pragma unroll
    for (int tk = 0; tk < 4; ++tk)
#pragma unroll
        for (int tq = 0; tq < 4; ++tq)
            acc[tk][tq] = __builtin_amdgcn_mfma_f32_16x16x32_bf16(kf[tk], qf[tq], acc[tk][tq], 0, 0, 0);

    __syncthreads();

    const float scale = 0.17677669529663688f;
    int qh[4], qwv[4];
#pragma unroll
    for (int tq = 0; tq < 4; ++tq) { int q = tq * 16 + lr; qh[tq] = q >> 3; qwv[tq] = q & 7; }
    float mx[4] = {-1e30f, -1e30f, -1e30f, -1e30f};
#pragma unroll
    for (int tk = 0; tk < 4; ++tk)
#pragma unroll
        for (int r = 0; r < 4; ++r) {
            int key = tk * 16 + lg * 4 + r;
            int kh = key >> 3, kw = key & 7;
#pragma unroll
            for (int tq = 0; tq < 4; ++tq) {
                float v = acc[tk][tq][r] * scale + rel_s[(qh[tq] - kh + 7) * 15 + (qwv[tq] - kw + 7)];
                acc[tk][tq][r] = v;
                mx[tq] = fmaxf(mx[tq], v);
            }
        }
#pragma unroll
    for (int tq = 0; tq < 4; ++tq) {
        mx[tq] = fmaxf(mx[tq], __shfl_xor(mx[tq], 16));
        mx[tq] = fmaxf(mx[tq], __shfl_xor(mx[tq], 32));
    }
    float sm[4] = {0.f, 0.f, 0.f, 0.f};
#pragma unroll
    for (int tk = 0; tk < 4; ++tk)
#pragma unroll
        for (int tq = 0; tq < 4; ++tq)
#pragma unroll
            for (int r = 0; r < 4; ++r) {
                float e = __expf(acc[tk][tq][r] - mx[tq]);
                acc[tk][tq][r] = e;
                sm[tq] += e;
            }
    float inv[4];
#pragma unroll
    for (int tq = 0; tq < 4; ++tq) {
        float s = sm[tq];
        s += __shfl_xor(s, 16);
        s += __shfl_xor(s, 32);
        inv[tq] = 1.0f / s;
    }
#pragma unroll
    for (int tq = 0; tq < 4; ++tq)
#pragma unroll
        for (int tk = 0; tk < 4; ++tk) {
            u16x4 pk = { f2bf(acc[tk][tq][0] * inv[tq]), f2bf(acc[tk][tq][1] * inv[tq]),
                         f2bf(acc[tk][tq][2] * inv[tq]), f2bf(acc[tk][tq][3] * inv[tq]) };
            *(u16x4*)&Pl[wv][tq * 16 + lr][tk * 16 + lg * 4] = pk;
        }

    __syncthreads();

    f32x4 o[4][2];
#pragma unroll
    for (int mq = 0; mq < 4; ++mq)
#pragma unroll
        for (int nd = 0; nd < 2; ++nd) o[mq][nd] = (f32x4){0.f, 0.f, 0.f, 0.f};
#pragma unroll
    for (int ks = 0; ks < 2; ++ks) {
        bf16x8 Af[4];
#pragma unroll
        for (int mq = 0; mq < 4; ++mq) {
            u16x4 lo = *(const u16x4*)&Pl[wv][mq * 16 + lr][ks * 32 + lg * 8];
            u16x4 hi = *(const u16x4*)&Pl[wv][mq * 16 + lr][ks * 32 + lg * 8 + 4];
#pragma unroll
            for (int c = 0; c < 4; ++c) { Af[mq][c] = (short)lo[c]; Af[mq][c + 4] = (short)hi[c]; }
        }
        bf16x8 Bf[2];
#pragma unroll
        for (int nd = 0; nd < 2; ++nd)
#pragma unroll
            for (int j = 0; j < 8; ++j)
                Bf[nd][j] = (short)Vl[wv][ks * 32 + lg * 8 + j][nd * 16 + lr];
#pragma unroll
        for (int mq = 0; mq < 4; ++mq)
#pragma unroll
            for (int nd = 0; nd < 2; ++nd)
                o[mq][nd] = __builtin_amdgcn_mfma_f32_16x16x32_bf16(Af[mq], Bf[nd], o[mq][nd], 0, 0, 0);
    }

#pragma unroll
    for (int mq = 0; mq < 4; ++mq)
#pragma unroll
        for (int nd = 0; nd < 2; ++nd)
#pragma unroll
            for (int r = 0; r < 4; ++r) {
                int q = mq * 16 + lg * 4 + r;
                int pix = (wy * 8 + (q >> 3)) * IW + wx * 8 + (q & 7);
                qatt[((size_t)b * NPIX + pix) * CCH + head * HDIM + nd * 16 + lr] = f2bf(o[mq][nd][r]);
            }
}

// ---------------------------------------------------------------------------
// K5: projection via bf16 MFMA (W from bf16 wp).
// ---------------------------------------------------------------------------
__global__ __launch_bounds__(256) void k5_mfma(const unsigned short* __restrict__ att,
                                               const unsigned short* __restrict__ wp,
                                               const float* __restrict__ proj_b,
                                               float* __restrict__ out) {
    constexpr int BN = 128, KC = 64, KCP = 72;
    __shared__ unsigned short Ws[CCH][KCP];
    __shared__ unsigned short Xt[BN][KCP];
    int px0 = blockIdx.x * BN;
    int b = blockIdx.y;
    int tid = threadIdx.x;
    int wv = tid >> 6, lane = tid & 63, lr = lane & 15, lg = lane >> 4;

    f32x4 acc[3][8];
#pragma unroll
    for (int i = 0; i < 3; ++i)
#pragma unroll
        for (int j = 0; j < 8; ++j) acc[i][j] = (f32x4){0.f, 0.f, 0.f, 0.f};

    int spx = tid & 127, skg = tid >> 7;

    for (int k0 = 0; k0 < CCH; k0 += KC) {
#pragma unroll
        for (int i = 0; i < 6; ++i) {
            int u = tid + 256 * i;
            int o = u >> 3, kb8 = u & 7;
            *(u16x8*)&Ws[o][kb8 * 8] = *(const u16x8*)&wp[(size_t)o * CCH + k0 + kb8 * 8];
        }
        {
            const unsigned short* arow = &att[((size_t)b * NPIX + px0 + spx) * CCH + k0 + skg * 32];
#pragma unroll
            for (int j8 = 0; j8 < 4; ++j8)
                *(u16x8*)&Xt[spx][skg * 32 + j8 * 8] = *(const u16x8*)&arow[j8 * 8];
        }
        __syncthreads();
#pragma unroll
        for (int kk = 0; kk < KC; kk += 32) {
            bf16x8 af[3], bfr[8];
#pragma unroll
            for (int i = 0; i < 3; ++i)
                af[i] = *(const bf16x8*)&Ws[wv * 48 + i * 16 + lr][kk + lg * 8];
#pragma unroll
            for (int j = 0; j < 8; ++j)
                bfr[j] = *(const bf16x8*)&Xt[j * 16 + lr][kk + lg * 8];
#pragma unroll
            for (int i = 0; i < 3; ++i)
#pragma unroll
                for (int j = 0; j < 8; ++j)
                    acc[i][j] = __builtin_amdgcn_mfma_f32_16x16x32_bf16(af[i], bfr[j], acc[i][j], 0, 0, 0);
        }
        __syncthreads();
    }

#pragma unroll
    for (int i = 0; i < 3; ++i) {
        int och = wv * 48 + i * 16 + lg * 4;
#pragma unroll
        for (int r = 0; r < 4; ++r) {
            float bias = proj_b[och + r];
            size_t base = (size_t)(b * CCH + och + r) * NPIX + px0 + lr;
#pragma unroll
            for (int j = 0; j < 8; ++j)
                out[base + j * 16] = acc[i][j][r] + bias;
        }
    }
}

// ---------------------------------------------------------------------------
extern "C" void kernel_launch(void* const* d_in, const int* in_sizes, int n_in,
                              void* d_out, int out_size, void* d_ws, size_t ws_size,
                              hipStream_t stream) {
    const float* x = (const float*)d_in[0];
    const float* var = (const float*)d_in[1];
    const float* qkv_w = (const float*)d_in[2];
    const float* qkv_b = (const float*)d_in[3];
    const float* bias_w = (const float*)d_in[4];
    const float* bias_b = (const float*)d_in[5];
    const float* scale_w = (const float*)d_in[6];
    const float* scale_b = (const float*)d_in[7];
    const float* proj_w = (const float*)d_in[8];
    const float* proj_b = (const float*)d_in[9];
    const float* rel_table = (const float*)d_in[10];
    float* out = (float*)d_out;

    char* ws = (char*)d_ws;
    float* pooled = (float*)ws;                           // 1,572,864 B
    float* sb = (float*)(ws + 1572864ull);                // 196,608 B
    const size_t elemQ = (size_t)BB * CCH * NPIX;         // 25,165,824
    unsigned short* q = (unsigned short*)(ws + 1769472ull);
    unsigned short* k = q + elemQ;
    unsigned short* v = k + elemQ;
    unsigned short* wbf = v + elemQ;                      // 147,456 u16
    unsigned short* wq_bf = wbf;
    unsigned short* wp_bf = wbf + 110592;
    unsigned short* xt = wbf + 147456;

    size_t need_base = 1769472ull + 3ull * elemQ * 2 + 294912ull;
    size_t need_fast = need_base + elemQ * 2;
    if (ws_size < need_base) return;
    bool fast = ws_size >= need_fast;

    mega1<<<dim3(72 + (fast ? 3584 : 1536)), dim3(512), 0, stream>>>(
        x, var, pooled, xt, qkv_w, proj_w, wbf, fast ? 1 : 0);

    if (fast) {
        mega2<true><<<dim3(3584), dim3(256), 0, stream>>>(x, xt, wq_bf, qkv_b, q, k, v,
                                                          pooled, bias_w, bias_b, scale_w, scale_b, sb);
    } else {
        mega2<false><<<dim3(3584), dim3(256), 0, stream>>>(x, xt, wq_bf, qkv_b, q, k, v,
                                                           pooled, bias_w, bias_b, scale_w, scale_b, sb);
    }

    k4_attn<<<dim3(NWIN / 4, NH, BB), dim3(256), 0, stream>>>(q, k, v, sb, rel_table);
    k5_mfma<<<dim3(NPIX / 128, BB), dim3(256), 0, stream>>>(q, wp_bf, proj_b, out);
}